// Round 15
// baseline (620.946 us; speedup 1.0000x reference)
//
#include <hip/hip_runtime.h>

#define NN 20000
#define NE 640000
#define NR 8
#define NB 8
#define HID 256
#define KPOI 12
#define KTIME 2880
#define KROAD 128
#define NK (NN * NR)    // 160000 (dst,rel) keys
#define NS 9            // 8 relations + self
#define KCAT (NS * HID) // 2304
#define TROWS 11        // time-GEMM rows per block
#define TLROW 5776      // LDS bytes per A row (2880*2 + 16 pad -> bank 4r)

typedef __attribute__((ext_vector_type(8))) short bf8_t;   // 8 bf16 = 4 VGPR
typedef __attribute__((ext_vector_type(4))) float f4_t;

__device__ inline unsigned short f2bf(float f) {  // RNE f32->bf16
  unsigned int u = __float_as_uint(f);
  u += 0x7FFF + ((u >> 16) & 1);
  return (unsigned short)(u >> 16);
}
__device__ inline float bf2f(unsigned short h) {
  return __uint_as_float((unsigned int)h << 16);
}

// async global->LDS, 16B per lane; LDS dest = wave-uniform base + lane*16
__device__ inline void gl_lds16(const void* g, void* l) {
  __builtin_amdgcn_global_load_lds(
      (const __attribute__((address_space(1))) void*)g,
      (__attribute__((address_space(3))) void*)l, 16, 0, 0);
}

// ---------------- f32 GEMM tile body (poi/road projections) ----------------
#define BK 16
__device__ inline void sgemm_body(
    int M, int Nn, int K,
    const float* __restrict__ A, int lda,
    const float* __restrict__ B, int ldb,
    const float* __restrict__ bias,
    unsigned short* __restrict__ C, int ldc, int brow, char* lds)
{
  constexpr int BM = 64, BN = 64, TM = 4, TN = 4;
  constexpr int SA = BM + 4;
  constexpr int SB = BN + 4;
  float* As = (float*)lds;
  float* Bs = (float*)(lds + 4352);
  const int tid = threadIdx.x;
  constexpr int TCOLS = BN / TN;
  const int row0 = (tid / TCOLS) * TM;
  const int col0 = (tid % TCOLS) * TN;

  float acc[TM][TN] = {};

  for (int kb = 0; kb < K; kb += BK) {
    {
      int i = tid;
      int r = i >> 2, q = (i & 3) * 4;
      int grow = brow + r, gk = kb + q;
      if (grow < M && gk + 3 < K) {
        float4 v = *(const float4*)(A + (size_t)grow * lda + gk);
        As[(q + 0) * SA + r] = v.x;
        As[(q + 1) * SA + r] = v.y;
        As[(q + 2) * SA + r] = v.z;
        As[(q + 3) * SA + r] = v.w;
      } else {
#pragma unroll
        for (int j = 0; j < 4; ++j)
          As[(q + j) * SA + r] =
              (grow < M && gk + j < K) ? A[(size_t)grow * lda + gk + j] : 0.f;
      }
    }
    {
      int i = tid;
      int k = i / (BN / 4), cq = (i % (BN / 4)) * 4;
      int gk = kb + k;
      float4 v = {0.f, 0.f, 0.f, 0.f};
      if (gk < K) {
        if (cq + 3 < Nn) {
          v = *(const float4*)(B + (size_t)gk * ldb + cq);
        } else {
#pragma unroll
          for (int j = 0; j < 4; ++j)
            if (cq + j < Nn) (&v.x)[j] = B[(size_t)gk * ldb + cq + j];
        }
      }
      *(float4*)(&Bs[k * SB + cq]) = v;
    }
    __syncthreads();
#pragma unroll
    for (int kk = 0; kk < BK; ++kk) {
      float a[TM], bb[TN];
      *(float4*)(&a[0]) = *(const float4*)(&As[kk * SA + row0]);
      *(float4*)(&bb[0]) = *(const float4*)(&Bs[kk * SB + col0]);
#pragma unroll
      for (int i = 0; i < TM; ++i)
#pragma unroll
        for (int j = 0; j < TN; ++j)
          acc[i][j] += a[i] * bb[j];
    }
    __syncthreads();
  }

  float bcache[TN];
#pragma unroll
  for (int j = 0; j < TN; ++j) bcache[j] = bias[col0 + j];
#pragma unroll
  for (int i = 0; i < TM; ++i) {
    int row = brow + row0 + i;
    if (row >= M) continue;
#pragma unroll
    for (int j = 0; j < TN; ++j)
      C[(size_t)row * ldc + col0 + j] = f2bf(acc[i][j] + bcache[j]);
  }
}

// ---------------- merged hist + weight-prep + poi/road projections ---------
__global__ __launch_bounds__(256) void hist_prep_k(
    const int* __restrict__ dstp, const int* __restrict__ etp,
    int* __restrict__ counts,
    const float* __restrict__ loop_w1, const float* __restrict__ loop_w2,
    const float* __restrict__ time_w,
    const float* __restrict__ coef1, const float* __restrict__ basis1,
    const float* __restrict__ coef2, const float* __restrict__ basis2,
    const float* __restrict__ poi_dist, const float* __restrict__ poi_w,
    const float* __restrict__ poi_b,
    const float* __restrict__ road_feat, const float* __restrict__ road_w,
    const float* __restrict__ road_b,
    unsigned short* __restrict__ Wc1, unsigned short* __restrict__ Wc2,
    unsigned short* __restrict__ TWT, unsigned short* __restrict__ hbuf)
{
  __shared__ __align__(16) char lds[8704];
  int b = blockIdx.x;
  if (b < 2500) {   // histogram: 2500*256 == NE exactly
    int e = b * 256 + threadIdx.x;
    atomicAdd(&counts[dstp[e] * NR + etp[e]], 1);
    return;
  }
  b -= 2500;
  const int to = threadIdx.x & 63;
  const int tq = threadIdx.x >> 6;

  if (b < 378) {
    unsigned short (*T)[66] = (unsigned short (*)[66])lds;
    if (b < 256) {        // Wc[lr][o][r*256+i] = sum_q coef*basis[q][i][o]
      const int lr = b >> 4;
      const int tile = b & 15;
      const int i0 = ((tile >> 2) & 3) * 64, o0 = (tile & 3) * 64;
      const float* coef  = (lr < NR) ? coef1 : coef2;
      const float* basis = (lr < NR) ? basis1 : basis2;
      unsigned short* Wc = (lr < NR) ? Wc1 : Wc2;
      const int r = lr & 7;
      float cf[NB];
#pragma unroll
      for (int q = 0; q < NB; ++q) cf[q] = coef[r * NB + q];
#pragma unroll
      for (int k = 0; k < 16; ++k) {
        int i_loc = tq * 16 + k;
        int i = i0 + i_loc;
        float acc = 0.f;
#pragma unroll
        for (int q = 0; q < NB; ++q)
          acc += cf[q] * basis[((size_t)(q * HID + i)) * HID + o0 + to];
        T[i_loc][to] = f2bf(acc);
      }
      __syncthreads();
#pragma unroll
      for (int k = 0; k < 16; ++k) {
        int o_loc = tq * 16 + k;
        Wc[(size_t)(o0 + o_loc) * KCAT + r * HID + i0 + to] = T[to][o_loc];
      }
    } else if (b < 288) { // Wc[l][o][2048+i] = loop_w_l[i][o]
      const int j = b - 256;
      const int layer = j >> 4;
      const int tile = j & 15;
      const int i0 = ((tile >> 2) & 3) * 64, o0 = (tile & 3) * 64;
      const float* lw = layer ? loop_w2 : loop_w1;
      unsigned short* Wc = layer ? Wc2 : Wc1;
#pragma unroll
      for (int k = 0; k < 16; ++k) {
        int i_loc = tq * 16 + k;
        T[i_loc][to] = f2bf(lw[(size_t)(i0 + i_loc) * HID + o0 + to]);
      }
      __syncthreads();
#pragma unroll
      for (int k = 0; k < 16; ++k) {
        int o_loc = tq * 16 + k;
        Wc[(size_t)(o0 + o_loc) * KCAT + NR * HID + i0 + to] = T[to][o_loc];
      }
    } else {              // TWT[c][r] = time_w[r][c], tiled 64x64
      const int j = b - 288;
      const int r0 = (j >> 1) * 64, c0 = (j & 1) * 64;
#pragma unroll
      for (int k = 0; k < 16; ++k) {
        int r_loc = tq * 16 + k;
        T[r_loc][to] = f2bf(time_w[(size_t)(r0 + r_loc) * 128 + c0 + to]);
      }
      __syncthreads();
#pragma unroll
      for (int k = 0; k < 16; ++k) {
        int c_loc = tq * 16 + k;
        TWT[(size_t)(c0 + c_loc) * KTIME + r0 + to] = T[to][c_loc];
      }
    }
  } else if (b < 691) {   // poi projection -> hbuf cols [0,64)
    sgemm_body(NN, 64, KPOI, poi_dist, KPOI, poi_w, 64, poi_b,
               hbuf + 0, HID, (b - 378) * 64, lds);
  } else {                // road projection -> hbuf cols [192,256)
    sgemm_body(NN, 64, KROAD, road_feat, KROAD, road_w, 64, road_b,
               hbuf + 192, HID, (b - 691) * 64, lds);
  }
}

// ---------------- merged scan: parallel cross-block base -------------------
__global__ __launch_bounds__(256) void scan_all(
    const int* __restrict__ counts, int* __restrict__ offs,
    int* __restrict__ cursor, int* __restrict__ bsums,
    int* __restrict__ counter) {
  __shared__ int sh[256];
  const int bid = blockIdx.x;
  const int t = threadIdx.x;
  const int nblk = gridDim.x;
  const int gbase = bid * 1024;
  int v[4], run[4];
  int s = 0;
#pragma unroll
  for (int j = 0; j < 4; ++j) {
    int idx = gbase + t * 4 + j;
    v[j] = (idx < NK) ? counts[idx] : 0;
    s += v[j];
  }
  sh[t] = s;
  __syncthreads();
  for (int off = 1; off < 256; off <<= 1) {
    int x = (t >= off) ? sh[t - off] : 0;
    __syncthreads();
    sh[t] += x;
    __syncthreads();
  }
  {
    int r = sh[t] - s;
#pragma unroll
    for (int j = 0; j < 4; ++j) { run[j] = r; r += v[j]; }
  }
  if (t == 255) {
    bsums[bid] = sh[255];
    __threadfence();
    atomicAdd(counter, 1);
  }
  if (t == 0) {
    while (atomicAdd(counter, 0) < nblk) {}
    __threadfence();
  }
  __syncthreads();
  int bs = (t < nblk) ? atomicAdd(&bsums[t], 0) : 0;
  __syncthreads();
  sh[t] = bs;
  __syncthreads();
  for (int off = 1; off < 256; off <<= 1) {
    int x = (t >= off) ? sh[t - off] : 0;
    __syncthreads();
    sh[t] += x;
    __syncthreads();
  }
  const int base = (bid > 0) ? sh[bid - 1] : 0;
#pragma unroll
  for (int j = 0; j < 4; ++j) {
    int idx = gbase + t * 4 + j;
    if (idx < NK) {
      int val = run[j] + base;
      offs[idx] = val;
      cursor[idx] = val;
    }
  }
  if (bid == 0 && t == 0) offs[NK] = NE;
}

// ---------------- CSR fill (standalone, high-TLP) ---------------------------
__global__ __launch_bounds__(256) void fill_k(const int* __restrict__ src,
                                              const int* __restrict__ dst,
                                              const int* __restrict__ et,
                                              int* __restrict__ cursor,
                                              unsigned short* __restrict__ ssrc) {
  int e = blockIdx.x * 256 + threadIdx.x;
  if (e < NE) {
    int key = dst[e] * NR + et[e];
    int p = atomicAdd(&cursor[key], 1);
    ssrc[p] = (unsigned short)src[e];
  }
}

// ---------------- time GEMM, DRAM-sequential staging ------------------------
// block = 11 rows x 512 thr; A rows staged ONCE as one contiguous 127-KB
// sweep (f32 -> bf16 into padded LDS rows); 8 waves split K (steps s=w,w+8,..);
// B fragments per-lane from L2-resident BT; LDS-atomic f32 reduce + bias.
__global__ __launch_bounds__(512) void time_k(
    const float* __restrict__ A,            // [NN][2880] f32
    const unsigned short* __restrict__ BT,  // [128][2880] bf16
    const float* __restrict__ bias,         // [128]
    unsigned short* __restrict__ featb)     // [NN][256], cols 64..191
{
  __shared__ __align__(16) char lds[TROWS * TLROW];   // 63,536 B
  const int tid = threadIdx.x;
  const int lane = tid & 63;
  const int w = tid >> 6;
  const int brow = blockIdx.x * TROWS;

  // ---- stage: block's 11 rows = one contiguous global region, swept linearly
  const int CHUNKS = TROWS * 360;   // 3960 chunks of 8 f32 (32 B)
  for (int c = tid; c < CHUNKS; c += 512) {
    int r = c / 360;
    int k8 = (c - r * 360) * 8;
    int grow = brow + r;
    unsigned short hh[8] = {0, 0, 0, 0, 0, 0, 0, 0};
    if (grow < NN) {
      const float* ap = A + (size_t)grow * KTIME + k8;
      f4_t v0 = *(const f4_t*)ap;
      f4_t v1 = *(const f4_t*)(ap + 4);
#pragma unroll
      for (int j = 0; j < 4; ++j) { hh[j] = f2bf(v0[j]); hh[4 + j] = f2bf(v1[j]); }
    }
    *(bf8_t*)(lds + r * TLROW + k8 * 2) = *(bf8_t*)hh;
  }
  __syncthreads();

  // ---- compute: wave w does k-steps s = w, w+8, ... (90 steps of K=32) ----
  f4_t acc[8];
#pragma unroll
  for (int t = 0; t < 8; ++t) acc[t] = (f4_t){0.f, 0.f, 0.f, 0.f};
  const int rA = lane & 15;
  const int q8 = (lane >> 4) * 8;
  for (int s = w; s < 90; s += 8) {
    int koff = s * 32 + q8;
    bf8_t af = *(const bf8_t*)(lds + rA * TLROW + koff * 2);
#pragma unroll
    for (int t = 0; t < 8; ++t) {
      bf8_t bf = *(const bf8_t*)(BT + (size_t)(t * 16 + rA) * KTIME + koff);
      acc[t] = __builtin_amdgcn_mfma_f32_16x16x32_bf16(af, bf, acc[t], 0, 0, 0);
    }
  }
  __syncthreads();

  // ---- reduce K-partials across waves via LDS atomics ----
  float* P = (float*)lds;   // TROWS*128 f32 = 5632 B (reuses A region)
  if (tid < TROWS * 32) *(f4_t*)(P + tid * 4) = (f4_t){0.f, 0.f, 0.f, 0.f};
  __syncthreads();
  const int rq = (lane >> 4) * 4;
#pragma unroll
  for (int t = 0; t < 8; ++t)
#pragma unroll
    for (int j = 0; j < 4; ++j)
      if (rq + j < TROWS)
        atomicAdd(&P[(rq + j) * 128 + t * 16 + rA], acc[t][j]);
  __syncthreads();
  if (tid < TROWS * 32) {
    int row = tid >> 5, c4 = (tid & 31) * 4;
    int grow = brow + row;
    if (grow < NN) {
      f4_t v = *(const f4_t*)(P + row * 128 + c4);
      f4_t b = *(const f4_t*)(bias + c4);
      unsigned short h[4] = {f2bf(v.x + b.x), f2bf(v.y + b.y),
                             f2bf(v.z + b.z), f2bf(v.w + b.w)};
      *(ushort4*)(featb + (size_t)grow * 256 + 64 + c4) = *(ushort4*)h;
    }
  }
}

// ---------------- CSR aggregation: one wave per dst, all 9 slices ----------
__global__ __launch_bounds__(256) void agg_k(
    const int* __restrict__ offs, const unsigned short* __restrict__ ssrc,
    const unsigned short* __restrict__ hin, unsigned short* __restrict__ Zc) {
  int d = (blockIdx.x * 256 + threadIdx.x) >> 6;
  int lane = threadIdx.x & 63;
  if (d >= NN) return;
  unsigned short* zrow = Zc + (size_t)d * KCAT;
  *(ushort4*)(zrow + NR * HID + lane * 4) =
      *(const ushort4*)(hin + (size_t)d * HID + lane * 4);
  int ob[NR + 1];
#pragma unroll
  for (int r = 0; r <= NR; ++r) ob[r] = offs[d * NR + r];
#pragma unroll 1
  for (int q = 0; q < NR; ++q) {
    int e = ob[q], hi = ob[q + 1];
    f4_t az = {0.f, 0.f, 0.f, 0.f};
    for (; e + 4 <= hi; e += 4) {
      int s0 = ssrc[e], s1 = ssrc[e + 1], s2 = ssrc[e + 2], s3 = ssrc[e + 3];
      ushort4 u0 = *(const ushort4*)(hin + (size_t)s0 * HID + lane * 4);
      ushort4 u1 = *(const ushort4*)(hin + (size_t)s1 * HID + lane * 4);
      ushort4 u2 = *(const ushort4*)(hin + (size_t)s2 * HID + lane * 4);
      ushort4 u3 = *(const ushort4*)(hin + (size_t)s3 * HID + lane * 4);
      az.x += (bf2f(u0.x) + bf2f(u1.x)) + (bf2f(u2.x) + bf2f(u3.x));
      az.y += (bf2f(u0.y) + bf2f(u1.y)) + (bf2f(u2.y) + bf2f(u3.y));
      az.z += (bf2f(u0.z) + bf2f(u1.z)) + (bf2f(u2.z) + bf2f(u3.z));
      az.w += (bf2f(u0.w) + bf2f(u1.w)) + (bf2f(u2.w) + bf2f(u3.w));
    }
    for (; e < hi; ++e) {
      int s = ssrc[e];
      ushort4 u = *(const ushort4*)(hin + (size_t)s * HID + lane * 4);
      az.x += bf2f(u.x); az.y += bf2f(u.y);
      az.z += bf2f(u.z); az.w += bf2f(u.w);
    }
    unsigned short hz[4] = {f2bf(az.x), f2bf(az.y), f2bf(az.z), f2bf(az.w)};
    *(ushort4*)(zrow + q * HID + lane * 4) = *(ushort4*)hz;
  }
}

// ---------------- layer GEMM: C[64x256] = Zcat @ Wcat + bias ---------------
template<int EPI>
__global__ __launch_bounds__(512) void gemm_cat(
    const unsigned short* __restrict__ Zc,    // [NN][KCAT]
    const unsigned short* __restrict__ Wc,    // [256][KCAT]
    const float* __restrict__ bias,
    float* __restrict__ C, unsigned short* __restrict__ hb)
{
  __shared__ __align__(16) char At[64 * 128];    // 8 KB
  __shared__ __align__(16) char Bt[256 * 128];   // 32 KB
  const int tid = threadIdx.x;
  const int lane = tid & 63;
  const int w = tid >> 6;
  const int wm = w >> 2;         // rows wm*32..+31
  const int wn = w & 3;          // cols wn*64..+63
  const int brow = blockIdx.x * 64;
  const bool full = (brow + 64 <= NN);
  const int c8sw = (lane & 7) ^ (lane >> 3);

  f4_t acc[2][4];
#pragma unroll
  for (int i = 0; i < 2; ++i)
#pragma unroll
    for (int j = 0; j < 4; ++j) acc[i][j] = (f4_t){0.f, 0.f, 0.f, 0.f};

  for (int kb = 0; kb < KCAT; kb += 64) {
    if (full) {  // A via global_load_lds: wave w -> rows w*8..w*8+7
      int row = (w << 3) + (lane >> 3);
      gl_lds16(Zc + (size_t)(brow + row) * KCAT + kb + c8sw * 8,
               At + (w << 10));
    } else {     // guarded reg-staged fallback (last block only)
      int r = tid >> 3, c8 = tid & 7;
      int grow = brow + r;
      bf8_t v = {0, 0, 0, 0, 0, 0, 0, 0};
      if (grow < NN) v = *(const bf8_t*)(Zc + (size_t)grow * KCAT + kb + c8 * 8);
      *(bf8_t*)(At + r * 128 + ((c8 * 16) ^ ((r & 7) << 4))) = v;
    }
#pragma unroll
    for (int it = 0; it < 4; ++it) {  // B via global_load_lds
      int n0 = (w << 3) + it * 64;
      int n = n0 + (lane >> 3);
      gl_lds16(Wc + (size_t)n * KCAT + kb + c8sw * 8, Bt + n0 * 128);
    }
    __syncthreads();
#pragma unroll
    for (int ks = 0; ks < 2; ++ks) {
      const int kbyte = ks * 64 + (lane >> 4) * 16;
      bf8_t af[2], bfr[4];
#pragma unroll
      for (int mi = 0; mi < 2; ++mi) {
        int m = wm * 32 + mi * 16 + (lane & 15);
        af[mi] = *(const bf8_t*)(At + m * 128 + (kbyte ^ ((m & 7) << 4)));
      }
#pragma unroll
      for (int ni = 0; ni < 4; ++ni) {
        int n = wn * 64 + ni * 16 + (lane & 15);
        bfr[ni] = *(const bf8_t*)(Bt + n * 128 + (kbyte ^ ((n & 7) << 4)));
      }
#pragma unroll
      for (int mi = 0; mi < 2; ++mi)
#pragma unroll
        for (int ni = 0; ni < 4; ++ni)
          acc[mi][ni] = __builtin_amdgcn_mfma_f32_16x16x32_bf16(
              af[mi], bfr[ni], acc[mi][ni], 0, 0, 0);
    }
    __syncthreads();
  }

  const int rq = (lane >> 4) * 4;
  const int cl = lane & 15;
#pragma unroll
  for (int ni = 0; ni < 4; ++ni) {
    int c = wn * 64 + ni * 16 + cl;
    float bv = bias[c];
#pragma unroll
    for (int mi = 0; mi < 2; ++mi) {
#pragma unroll
      for (int j = 0; j < 4; ++j) {
        int row = brow + wm * 32 + mi * 16 + rq + j;
        if (row < NN) {
          size_t o = (size_t)row * HID + c;
          float v = acc[mi][ni][j] + bv;
          if (EPI == 0) C[o] = v;
          else          hb[o] = f2bf(fmaxf(v, 0.f));
        }
      }
    }
  }
}

extern "C" void kernel_launch(void* const* d_in, const int* in_sizes, int n_in,
                              void* d_out, int out_size, void* d_ws, size_t ws_size,
                              hipStream_t stream) {
  const int*   srcp      = (const int*)d_in[0];
  const int*   dstp      = (const int*)d_in[1];
  const int*   etypep    = (const int*)d_in[2];
  const float* poi_dist  = (const float*)d_in[3];
  const float* time_dist = (const float*)d_in[4];
  const float* road_feat = (const float*)d_in[5];
  const float* poi_w     = (const float*)d_in[6];
  const float* poi_b     = (const float*)d_in[7];
  const float* time_w    = (const float*)d_in[8];
  const float* time_b    = (const float*)d_in[9];
  const float* road_w    = (const float*)d_in[10];
  const float* road_b    = (const float*)d_in[11];
  const float* basis1    = (const float*)d_in[12];
  const float* coef1     = (const float*)d_in[13];
  const float* loop_w1   = (const float*)d_in[14];
  const float* bias1     = (const float*)d_in[15];
  const float* basis2    = (const float*)d_in[16];
  const float* coef2     = (const float*)d_in[17];
  const float* loop_w2   = (const float*)d_in[18];
  const float* bias2     = (const float*)d_in[19];

  float* out = (float*)d_out;

  // ws layout (bytes), total ~108.1 MB (ws_size ~921 MB):
  //   Wc1  bf16 @ 0           (1,179,648)   [256][2304]
  //   Wc2  bf16 @ 1,179,648   (1,179,648)
  //   TWT  bf16 @ 2,359,296   (737,280)
  //   hbuf bf16 @ 3,096,576   (10,240,000)  feat; then relu(h1)
  //   Zcat bf16 @ 13,336,576  (92,160,000)  [NN][2304]
  //   offs      @ 105,496,576 (640,016)
  //   bsums     @ 106,136,592 (1,024)
  //   ssrc u16  @ 106,137,616 (1,280,000)
  //   cursor    @ 107,417,616 (640,000)
  // aliases: counts+counter -> Zcat region (dead before Zcat's first write)
  char* ws = (char*)d_ws;
  unsigned short* Wc1    = (unsigned short*)(ws);
  unsigned short* Wc2    = (unsigned short*)(ws + 1179648);
  unsigned short* TWT    = (unsigned short*)(ws + 2359296);
  unsigned short* hbuf   = (unsigned short*)(ws + 3096576);
  unsigned short* Zcat   = (unsigned short*)(ws + 13336576);
  int*            offs   = (int*)  (ws + 105496576);
  int*            bsums  = (int*)  (ws + 106136592);
  unsigned short* ssrc   = (unsigned short*)(ws + 106137616);
  int*            cursor = (int*)  (ws + 107417616);
  int*            counts = (int*)Zcat;        // NK ints
  int*            counter = counts + NK;      // 1 int (spin counter)

  dim3 blk(256);

  // ---- zero counts + counter ----
  hipMemsetAsync(counts, 0, (NK + 1) * sizeof(int), stream);

  // ---- hist (2500 blocks) || weight prep + poi/road projections (1004) ----
  hist_prep_k<<<3504, blk, 0, stream>>>(dstp, etypep, counts,
                                        loop_w1, loop_w2, time_w,
                                        coef1, basis1, coef2, basis2,
                                        poi_dist, poi_w, poi_b,
                                        road_feat, road_w, road_b,
                                        Wc1, Wc2, TWT, hbuf);

  // ---- scan (157 resident blocks, parallel cross-block base) ----
  scan_all<<<(NK + 1023) / 1024, blk, 0, stream>>>(counts, offs, cursor,
                                                   bsums, counter);

  // ---- CSR fill (2500 blocks, high TLP) ----
  fill_k<<<(NE + 255) / 256, blk, 0, stream>>>(srcp, dstp, etypep, cursor, ssrc);

  // ---- time projection (sequential-stream staging) ----
  time_k<<<(NN + TROWS - 1) / TROWS, 512, 0, stream>>>(time_dist, TWT,
                                                       time_b, hbuf);

  // ---- layer 1 ----
  agg_k<<<NN * 64 / 256, blk, 0, stream>>>(offs, ssrc, hbuf, Zcat);
  gemm_cat<1><<<(NN + 63) / 64, 512, 0, stream>>>(Zcat, Wc1, bias1, nullptr, hbuf);

  // ---- layer 2 ----
  agg_k<<<NN * 64 / 256, blk, 0, stream>>>(offs, ssrc, hbuf, Zcat);
  gemm_cat<0><<<(NN + 63) / 64, 512, 0, stream>>>(Zcat, Wc2, bias2, out, nullptr);
}

// Round 16
// 398.969 us; speedup vs baseline: 1.5564x; 1.5564x over previous
//
#include <hip/hip_runtime.h>

#define NN 20000
#define NE 640000
#define NR 8
#define NB 8
#define HID 256
#define KPOI 12
#define KTIME 2880
#define KROAD 128
#define NK (NN * NR)    // 160000 (dst,rel) keys
#define NS 9            // 8 relations + self
#define KCAT (NS * HID) // 2304

typedef __attribute__((ext_vector_type(8))) short bf8_t;   // 8 bf16 = 4 VGPR
typedef __attribute__((ext_vector_type(4))) float f4_t;

__device__ inline unsigned short f2bf(float f) {  // RNE f32->bf16
  unsigned int u = __float_as_uint(f);
  u += 0x7FFF + ((u >> 16) & 1);
  return (unsigned short)(u >> 16);
}
__device__ inline float bf2f(unsigned short h) {
  return __uint_as_float((unsigned int)h << 16);
}

// async global->LDS, 16B per lane; LDS dest = wave-uniform base + lane*16
__device__ inline void gl_lds16(const void* g, void* l) {
  __builtin_amdgcn_global_load_lds(
      (const __attribute__((address_space(1))) void*)g,
      (__attribute__((address_space(3))) void*)l, 16, 0, 0);
}

// ---------------- f32 GEMM tile body (poi/road projections) ----------------
#define BK 16
__device__ inline void sgemm_body(
    int M, int Nn, int K,
    const float* __restrict__ A, int lda,
    const float* __restrict__ B, int ldb,
    const float* __restrict__ bias,
    unsigned short* __restrict__ C, int ldc, int brow, char* lds)
{
  constexpr int BM = 64, BN = 64, TM = 4, TN = 4;
  constexpr int SA = BM + 4;
  constexpr int SB = BN + 4;
  float* As = (float*)lds;
  float* Bs = (float*)(lds + 4352);
  const int tid = threadIdx.x;
  constexpr int TCOLS = BN / TN;
  const int row0 = (tid / TCOLS) * TM;
  const int col0 = (tid % TCOLS) * TN;

  float acc[TM][TN] = {};

  for (int kb = 0; kb < K; kb += BK) {
    {
      int i = tid;
      int r = i >> 2, q = (i & 3) * 4;
      int grow = brow + r, gk = kb + q;
      if (grow < M && gk + 3 < K) {
        float4 v = *(const float4*)(A + (size_t)grow * lda + gk);
        As[(q + 0) * SA + r] = v.x;
        As[(q + 1) * SA + r] = v.y;
        As[(q + 2) * SA + r] = v.z;
        As[(q + 3) * SA + r] = v.w;
      } else {
#pragma unroll
        for (int j = 0; j < 4; ++j)
          As[(q + j) * SA + r] =
              (grow < M && gk + j < K) ? A[(size_t)grow * lda + gk + j] : 0.f;
      }
    }
    {
      int i = tid;
      int k = i / (BN / 4), cq = (i % (BN / 4)) * 4;
      int gk = kb + k;
      float4 v = {0.f, 0.f, 0.f, 0.f};
      if (gk < K) {
        if (cq + 3 < Nn) {
          v = *(const float4*)(B + (size_t)gk * ldb + cq);
        } else {
#pragma unroll
          for (int j = 0; j < 4; ++j)
            if (cq + j < Nn) (&v.x)[j] = B[(size_t)gk * ldb + cq + j];
        }
      }
      *(float4*)(&Bs[k * SB + cq]) = v;
    }
    __syncthreads();
#pragma unroll
    for (int kk = 0; kk < BK; ++kk) {
      float a[TM], bb[TN];
      *(float4*)(&a[0]) = *(const float4*)(&As[kk * SA + row0]);
      *(float4*)(&bb[0]) = *(const float4*)(&Bs[kk * SB + col0]);
#pragma unroll
      for (int i = 0; i < TM; ++i)
#pragma unroll
        for (int j = 0; j < TN; ++j)
          acc[i][j] += a[i] * bb[j];
    }
    __syncthreads();
  }

  float bcache[TN];
#pragma unroll
  for (int j = 0; j < TN; ++j) bcache[j] = bias[col0 + j];
#pragma unroll
  for (int i = 0; i < TM; ++i) {
    int row = brow + row0 + i;
    if (row >= M) continue;
#pragma unroll
    for (int j = 0; j < TN; ++j)
      C[(size_t)row * ldc + col0 + j] = f2bf(acc[i][j] + bcache[j]);
  }
}

// ---------------- merged hist + weight-prep + poi/road projections ---------
__global__ __launch_bounds__(256) void hist_prep_k(
    const int* __restrict__ dstp, const int* __restrict__ etp,
    int* __restrict__ counts,
    const float* __restrict__ loop_w1, const float* __restrict__ loop_w2,
    const float* __restrict__ time_w,
    const float* __restrict__ coef1, const float* __restrict__ basis1,
    const float* __restrict__ coef2, const float* __restrict__ basis2,
    const float* __restrict__ poi_dist, const float* __restrict__ poi_w,
    const float* __restrict__ poi_b,
    const float* __restrict__ road_feat, const float* __restrict__ road_w,
    const float* __restrict__ road_b,
    unsigned short* __restrict__ Wc1, unsigned short* __restrict__ Wc2,
    unsigned short* __restrict__ TWT, unsigned short* __restrict__ hbuf)
{
  __shared__ __align__(16) char lds[8704];
  int b = blockIdx.x;
  if (b < 2500) {   // histogram: 2500*256 == NE exactly
    int e = b * 256 + threadIdx.x;
    atomicAdd(&counts[dstp[e] * NR + etp[e]], 1);
    return;
  }
  b -= 2500;
  const int to = threadIdx.x & 63;
  const int tq = threadIdx.x >> 6;

  if (b < 378) {
    unsigned short (*T)[66] = (unsigned short (*)[66])lds;
    if (b < 256) {        // Wc[lr][o][r*256+i] = sum_q coef*basis[q][i][o]
      const int lr = b >> 4;
      const int tile = b & 15;
      const int i0 = ((tile >> 2) & 3) * 64, o0 = (tile & 3) * 64;
      const float* coef  = (lr < NR) ? coef1 : coef2;
      const float* basis = (lr < NR) ? basis1 : basis2;
      unsigned short* Wc = (lr < NR) ? Wc1 : Wc2;
      const int r = lr & 7;
      float cf[NB];
#pragma unroll
      for (int q = 0; q < NB; ++q) cf[q] = coef[r * NB + q];
#pragma unroll
      for (int k = 0; k < 16; ++k) {
        int i_loc = tq * 16 + k;
        int i = i0 + i_loc;
        float acc = 0.f;
#pragma unroll
        for (int q = 0; q < NB; ++q)
          acc += cf[q] * basis[((size_t)(q * HID + i)) * HID + o0 + to];
        T[i_loc][to] = f2bf(acc);
      }
      __syncthreads();
#pragma unroll
      for (int k = 0; k < 16; ++k) {
        int o_loc = tq * 16 + k;
        Wc[(size_t)(o0 + o_loc) * KCAT + r * HID + i0 + to] = T[to][o_loc];
      }
    } else if (b < 288) { // Wc[l][o][2048+i] = loop_w_l[i][o]
      const int j = b - 256;
      const int layer = j >> 4;
      const int tile = j & 15;
      const int i0 = ((tile >> 2) & 3) * 64, o0 = (tile & 3) * 64;
      const float* lw = layer ? loop_w2 : loop_w1;
      unsigned short* Wc = layer ? Wc2 : Wc1;
#pragma unroll
      for (int k = 0; k < 16; ++k) {
        int i_loc = tq * 16 + k;
        T[i_loc][to] = f2bf(lw[(size_t)(i0 + i_loc) * HID + o0 + to]);
      }
      __syncthreads();
#pragma unroll
      for (int k = 0; k < 16; ++k) {
        int o_loc = tq * 16 + k;
        Wc[(size_t)(o0 + o_loc) * KCAT + NR * HID + i0 + to] = T[to][o_loc];
      }
    } else {              // TWT[c][r] = time_w[r][c], tiled 64x64
      const int j = b - 288;
      const int r0 = (j >> 1) * 64, c0 = (j & 1) * 64;
#pragma unroll
      for (int k = 0; k < 16; ++k) {
        int r_loc = tq * 16 + k;
        T[r_loc][to] = f2bf(time_w[(size_t)(r0 + r_loc) * 128 + c0 + to]);
      }
      __syncthreads();
#pragma unroll
      for (int k = 0; k < 16; ++k) {
        int c_loc = tq * 16 + k;
        TWT[(size_t)(c0 + c_loc) * KTIME + r0 + to] = T[to][c_loc];
      }
    }
  } else if (b < 691) {   // poi projection -> hbuf cols [0,64)
    sgemm_body(NN, 64, KPOI, poi_dist, KPOI, poi_w, 64, poi_b,
               hbuf + 0, HID, (b - 378) * 64, lds);
  } else {                // road projection -> hbuf cols [192,256)
    sgemm_body(NN, 64, KROAD, road_feat, KROAD, road_w, 64, road_b,
               hbuf + 192, HID, (b - 691) * 64, lds);
  }
}

// ---------------- merged scan: parallel cross-block base -------------------
__global__ __launch_bounds__(256) void scan_all(
    const int* __restrict__ counts, int* __restrict__ offs,
    int* __restrict__ cursor, int* __restrict__ bsums,
    int* __restrict__ counter) {
  __shared__ int sh[256];
  const int bid = blockIdx.x;
  const int t = threadIdx.x;
  const int nblk = gridDim.x;
  const int gbase = bid * 1024;
  int v[4], run[4];
  int s = 0;
#pragma unroll
  for (int j = 0; j < 4; ++j) {
    int idx = gbase + t * 4 + j;
    v[j] = (idx < NK) ? counts[idx] : 0;
    s += v[j];
  }
  sh[t] = s;
  __syncthreads();
  for (int off = 1; off < 256; off <<= 1) {
    int x = (t >= off) ? sh[t - off] : 0;
    __syncthreads();
    sh[t] += x;
    __syncthreads();
  }
  {
    int r = sh[t] - s;
#pragma unroll
    for (int j = 0; j < 4; ++j) { run[j] = r; r += v[j]; }
  }
  if (t == 255) {
    bsums[bid] = sh[255];
    __threadfence();
    atomicAdd(counter, 1);
  }
  if (t == 0) {
    while (atomicAdd(counter, 0) < nblk) {}
    __threadfence();
  }
  __syncthreads();
  int bs = (t < nblk) ? atomicAdd(&bsums[t], 0) : 0;
  __syncthreads();
  sh[t] = bs;
  __syncthreads();
  for (int off = 1; off < 256; off <<= 1) {
    int x = (t >= off) ? sh[t - off] : 0;
    __syncthreads();
    sh[t] += x;
    __syncthreads();
  }
  const int base = (bid > 0) ? sh[bid - 1] : 0;
#pragma unroll
  for (int j = 0; j < 4; ++j) {
    int idx = gbase + t * 4 + j;
    if (idx < NK) {
      int val = run[j] + base;
      offs[idx] = val;
      cursor[idx] = val;
    }
  }
  if (bid == 0 && t == 0) offs[NK] = NE;
}

// ---------------- merged fill + time GEMM -----------------------------------
// blocks [0,1250): CSR fill (1 edge/thread, 512 thr, exact).
// blocks [1250,1875): time GEMM; A staged 4 K-steps deep so each wave reads
// 1 KB CONTIGUOUS per row (DRAM page friendly) instead of 256-B slivers.
__global__ __launch_bounds__(512) void fill_time_k(
    const int* __restrict__ srcp, const int* __restrict__ dstp,
    const int* __restrict__ etp, int* __restrict__ cursor,
    unsigned short* __restrict__ ssrc,
    const float* __restrict__ A,            // [NN][2880] f32
    const unsigned short* __restrict__ BT,  // [128][2880] bf16
    const float* __restrict__ bias,         // [128]
    unsigned short* __restrict__ featb)     // [NN][256], cols 64..191
{
  __shared__ __align__(16) char lds[65536];
  int b = blockIdx.x;
  if (b < 1250) {   // fill: 1250*512 == NE exactly
    int e = b * 512 + threadIdx.x;
    int key = dstp[e] * NR + etp[e];
    int p = atomicAdd(&cursor[key], 1);
    ssrc[p] = (unsigned short)srcp[e];
    return;
  }
  b -= 1250;        // time-GEMM block index 0..624
  char* ldsA = lds;            // 32 KB: [sg][32r][4sub][128B]
  char* ldsB = lds + 32768;    // 32 KB: [sg][128n][128B]
  const int tid = threadIdx.x;
  const int lane = tid & 63;
  const int w = tid >> 6;        // 0..7
  const int g = w >> 2;          // K-group
  const int cb = w & 3;          // col block (32 cols)
  const int brow = b * 32;
  const int c8sw = (lane & 7) ^ (lane >> 3);   // swizzled source chunk (B)
  const int tsg = tid >> 8;      // staging K-group
  const int tr  = (tid >> 3) & 31;
  const int tc  = tid & 7;

  f4_t acc[2][2];
#pragma unroll
  for (int i = 0; i < 2; ++i)
#pragma unroll
    for (int j = 0; j < 2; ++j) acc[i][j] = (f4_t){0.f, 0.f, 0.f, 0.f};

  for (int sup = 0; sup < 6; ++sup) {
    // ---- stage A: 4 consecutive K-steps; per row the wave's 4 loads cover
    //      1 KB contiguous (page-friendly) ----
#pragma unroll
    for (int it = 0; it < 4; ++it) {
      int idx = sup * 4 + it;            // step within group
      int gstep = tsg * 23 + idx;
      unsigned short hh[8] = {0, 0, 0, 0, 0, 0, 0, 0};
      if (idx < 23 && gstep < 45) {
        const float* ap = A + (size_t)(brow + tr) * KTIME + gstep * 64 + tc * 8;
        f4_t v0 = *(const f4_t*)ap;
        f4_t v1 = *(const f4_t*)(ap + 4);
#pragma unroll
        for (int j = 0; j < 4; ++j) { hh[j] = f2bf(v0[j]); hh[4 + j] = f2bf(v1[j]); }
      }
      *(bf8_t*)(ldsA + tsg * 16384 + tr * 512 + it * 128 +
                ((tc * 16) ^ ((tr & 7) << 4))) = *(bf8_t*)hh;
    }
#pragma unroll 1
    for (int sub = 0; sub < 4; ++sub) {
      int idx = sup * 4 + sub;
#pragma unroll
      for (int it2 = 0; it2 < 4; ++it2) {  // stage B via global_load_lds
        int s0 = (w << 6) + it2 * 512;
        int sg = s0 >> 10;
        int r0 = (s0 >> 3) & 127;
        int step = sg * 23 + idx;
        if (idx < 23 && step < 45) {
          int rr = r0 + (lane >> 3);
          gl_lds16(BT + (size_t)rr * KTIME + step * 64 + c8sw * 8,
                   ldsB + sg * 16384 + r0 * 128);
        }
      }
      __syncthreads();
      if (idx < 23 && g * 23 + idx < 45) {
#pragma unroll
        for (int ks = 0; ks < 2; ++ks) {
          const int kbyte = ks * 64 + (lane >> 4) * 16;
          const int ch16 = (ks * 4 + (lane >> 4)) * 16;
          bf8_t af[2], bfr[2];
#pragma unroll
          for (int mi = 0; mi < 2; ++mi) {
            int m = mi * 16 + (lane & 15);
            af[mi] = *(const bf8_t*)(
                ldsA + g * 16384 + m * 512 + sub * 128 +
                (ch16 ^ ((m & 7) << 4)));
          }
#pragma unroll
          for (int ni = 0; ni < 2; ++ni) {
            int n = cb * 32 + ni * 16 + (lane & 15);
            bfr[ni] = *(const bf8_t*)(
                ldsB + g * 16384 + n * 128 + (kbyte ^ ((n & 7) << 4)));
          }
#pragma unroll
          for (int mi = 0; mi < 2; ++mi)
#pragma unroll
            for (int ni = 0; ni < 2; ++ni)
              acc[mi][ni] = __builtin_amdgcn_mfma_f32_16x16x32_bf16(
                  af[mi], bfr[ni], acc[mi][ni], 0, 0, 0);
        }
      }
      __syncthreads();
    }
  }

  // ---- cross-group reduce via LDS ----
  float* rb = (float*)ldsB;
  if (g == 1) {
#pragma unroll
    for (int mi = 0; mi < 2; ++mi)
#pragma unroll
      for (int ni = 0; ni < 2; ++ni)
#pragma unroll
        for (int j = 0; j < 4; ++j)
          rb[(cb * 64 + lane) * 16 + (mi * 2 + ni) * 4 + j] = acc[mi][ni][j];
  }
  __syncthreads();
  if (g == 0) {
    const int rq = (lane >> 4) * 4;
    const int cl = lane & 15;
#pragma unroll
    for (int ni = 0; ni < 2; ++ni) {
      int c = cb * 32 + ni * 16 + cl;
      float bv = bias[c];
#pragma unroll
      for (int mi = 0; mi < 2; ++mi) {
#pragma unroll
        for (int j = 0; j < 4; ++j) {
          float v = acc[mi][ni][j] +
                    rb[(cb * 64 + lane) * 16 + (mi * 2 + ni) * 4 + j] + bv;
          int row = brow + mi * 16 + rq + j;
          featb[(size_t)row * 256 + 64 + c] = f2bf(v);
        }
      }
    }
  }
}

// ---------------- CSR aggregation: one wave per dst, all 9 slices ----------
__global__ __launch_bounds__(256) void agg_k(
    const int* __restrict__ offs, const unsigned short* __restrict__ ssrc,
    const unsigned short* __restrict__ hin, unsigned short* __restrict__ Zc) {
  int d = (blockIdx.x * 256 + threadIdx.x) >> 6;
  int lane = threadIdx.x & 63;
  if (d >= NN) return;
  unsigned short* zrow = Zc + (size_t)d * KCAT;
  *(ushort4*)(zrow + NR * HID + lane * 4) =
      *(const ushort4*)(hin + (size_t)d * HID + lane * 4);
  int ob[NR + 1];
#pragma unroll
  for (int r = 0; r <= NR; ++r) ob[r] = offs[d * NR + r];
#pragma unroll 1
  for (int q = 0; q < NR; ++q) {
    int e = ob[q], hi = ob[q + 1];
    f4_t az = {0.f, 0.f, 0.f, 0.f};
    for (; e + 4 <= hi; e += 4) {
      int s0 = ssrc[e], s1 = ssrc[e + 1], s2 = ssrc[e + 2], s3 = ssrc[e + 3];
      ushort4 u0 = *(const ushort4*)(hin + (size_t)s0 * HID + lane * 4);
      ushort4 u1 = *(const ushort4*)(hin + (size_t)s1 * HID + lane * 4);
      ushort4 u2 = *(const ushort4*)(hin + (size_t)s2 * HID + lane * 4);
      ushort4 u3 = *(const ushort4*)(hin + (size_t)s3 * HID + lane * 4);
      az.x += (bf2f(u0.x) + bf2f(u1.x)) + (bf2f(u2.x) + bf2f(u3.x));
      az.y += (bf2f(u0.y) + bf2f(u1.y)) + (bf2f(u2.y) + bf2f(u3.y));
      az.z += (bf2f(u0.z) + bf2f(u1.z)) + (bf2f(u2.z) + bf2f(u3.z));
      az.w += (bf2f(u0.w) + bf2f(u1.w)) + (bf2f(u2.w) + bf2f(u3.w));
    }
    for (; e < hi; ++e) {
      int s = ssrc[e];
      ushort4 u = *(const ushort4*)(hin + (size_t)s * HID + lane * 4);
      az.x += bf2f(u.x); az.y += bf2f(u.y);
      az.z += bf2f(u.z); az.w += bf2f(u.w);
    }
    unsigned short hz[4] = {f2bf(az.x), f2bf(az.y), f2bf(az.z), f2bf(az.w)};
    *(ushort4*)(zrow + q * HID + lane * 4) = *(ushort4*)hz;
  }
}

// ---------------- layer GEMM: C[64x256] = Zcat @ Wcat + bias ---------------
template<int EPI>
__global__ __launch_bounds__(512) void gemm_cat(
    const unsigned short* __restrict__ Zc,    // [NN][KCAT]
    const unsigned short* __restrict__ Wc,    // [256][KCAT]
    const float* __restrict__ bias,
    float* __restrict__ C, unsigned short* __restrict__ hb)
{
  __shared__ __align__(16) char At[64 * 128];    // 8 KB
  __shared__ __align__(16) char Bt[256 * 128];   // 32 KB
  const int tid = threadIdx.x;
  const int lane = tid & 63;
  const int w = tid >> 6;
  const int wm = w >> 2;         // rows wm*32..+31
  const int wn = w & 3;          // cols wn*64..+63
  const int brow = blockIdx.x * 64;
  const bool full = (brow + 64 <= NN);
  const int c8sw = (lane & 7) ^ (lane >> 3);

  f4_t acc[2][4];
#pragma unroll
  for (int i = 0; i < 2; ++i)
#pragma unroll
    for (int j = 0; j < 4; ++j) acc[i][j] = (f4_t){0.f, 0.f, 0.f, 0.f};

  for (int kb = 0; kb < KCAT; kb += 64) {
    if (full) {  // A via global_load_lds: wave w -> rows w*8..w*8+7
      int row = (w << 3) + (lane >> 3);
      gl_lds16(Zc + (size_t)(brow + row) * KCAT + kb + c8sw * 8,
               At + (w << 10));
    } else {     // guarded reg-staged fallback (last block only)
      int r = tid >> 3, c8 = tid & 7;
      int grow = brow + r;
      bf8_t v = {0, 0, 0, 0, 0, 0, 0, 0};
      if (grow < NN) v = *(const bf8_t*)(Zc + (size_t)grow * KCAT + kb + c8 * 8);
      *(bf8_t*)(At + r * 128 + ((c8 * 16) ^ ((r & 7) << 4))) = v;
    }
#pragma unroll
    for (int it = 0; it < 4; ++it) {  // B via global_load_lds
      int n0 = (w << 3) + it * 64;
      int n = n0 + (lane >> 3);
      gl_lds16(Wc + (size_t)n * KCAT + kb + c8sw * 8, Bt + n0 * 128);
    }
    __syncthreads();
#pragma unroll
    for (int ks = 0; ks < 2; ++ks) {
      const int kbyte = ks * 64 + (lane >> 4) * 16;
      bf8_t af[2], bfr[4];
#pragma unroll
      for (int mi = 0; mi < 2; ++mi) {
        int m = wm * 32 + mi * 16 + (lane & 15);
        af[mi] = *(const bf8_t*)(At + m * 128 + (kbyte ^ ((m & 7) << 4)));
      }
#pragma unroll
      for (int ni = 0; ni < 4; ++ni) {
        int n = wn * 64 + ni * 16 + (lane & 15);
        bfr[ni] = *(const bf8_t*)(Bt + n * 128 + (kbyte ^ ((n & 7) << 4)));
      }
#pragma unroll
      for (int mi = 0; mi < 2; ++mi)
#pragma unroll
        for (int ni = 0; ni < 4; ++ni)
          acc[mi][ni] = __builtin_amdgcn_mfma_f32_16x16x32_bf16(
              af[mi], bfr[ni], acc[mi][ni], 0, 0, 0);
    }
    __syncthreads();
  }

  const int rq = (lane >> 4) * 4;
  const int cl = lane & 15;
#pragma unroll
  for (int ni = 0; ni < 4; ++ni) {
    int c = wn * 64 + ni * 16 + cl;
    float bv = bias[c];
#pragma unroll
    for (int mi = 0; mi < 2; ++mi) {
#pragma unroll
      for (int j = 0; j < 4; ++j) {
        int row = brow + wm * 32 + mi * 16 + rq + j;
        if (row < NN) {
          size_t o = (size_t)row * HID + c;
          float v = acc[mi][ni][j] + bv;
          if (EPI == 0) C[o] = v;
          else          hb[o] = f2bf(fmaxf(v, 0.f));
        }
      }
    }
  }
}

extern "C" void kernel_launch(void* const* d_in, const int* in_sizes, int n_in,
                              void* d_out, int out_size, void* d_ws, size_t ws_size,
                              hipStream_t stream) {
  const int*   srcp      = (const int*)d_in[0];
  const int*   dstp      = (const int*)d_in[1];
  const int*   etypep    = (const int*)d_in[2];
  const float* poi_dist  = (const float*)d_in[3];
  const float* time_dist = (const float*)d_in[4];
  const float* road_feat = (const float*)d_in[5];
  const float* poi_w     = (const float*)d_in[6];
  const float* poi_b     = (const float*)d_in[7];
  const float* time_w    = (const float*)d_in[8];
  const float* time_b    = (const float*)d_in[9];
  const float* road_w    = (const float*)d_in[10];
  const float* road_b    = (const float*)d_in[11];
  const float* basis1    = (const float*)d_in[12];
  const float* coef1     = (const float*)d_in[13];
  const float* loop_w1   = (const float*)d_in[14];
  const float* bias1     = (const float*)d_in[15];
  const float* basis2    = (const float*)d_in[16];
  const float* coef2     = (const float*)d_in[17];
  const float* loop_w2   = (const float*)d_in[18];
  const float* bias2     = (const float*)d_in[19];

  float* out = (float*)d_out;

  // ws layout (bytes), total ~108.1 MB (ws_size ~921 MB):
  //   Wc1  bf16 @ 0           (1,179,648)   [256][2304]
  //   Wc2  bf16 @ 1,179,648   (1,179,648)
  //   TWT  bf16 @ 2,359,296   (737,280)
  //   hbuf bf16 @ 3,096,576   (10,240,000)  feat; then relu(h1)
  //   Zcat bf16 @ 13,336,576  (92,160,000)  [NN][2304]
  //   offs      @ 105,496,576 (640,016)
  //   bsums     @ 106,136,592 (1,024)
  //   ssrc u16  @ 106,137,616 (1,280,000)
  //   cursor    @ 107,417,616 (640,000)
  // aliases: counts+counter -> Zcat region (dead before Zcat's first write)
  char* ws = (char*)d_ws;
  unsigned short* Wc1    = (unsigned short*)(ws);
  unsigned short* Wc2    = (unsigned short*)(ws + 1179648);
  unsigned short* TWT    = (unsigned short*)(ws + 2359296);
  unsigned short* hbuf   = (unsigned short*)(ws + 3096576);
  unsigned short* Zcat   = (unsigned short*)(ws + 13336576);
  int*            offs   = (int*)  (ws + 105496576);
  int*            bsums  = (int*)  (ws + 106136592);
  unsigned short* ssrc   = (unsigned short*)(ws + 106137616);
  int*            cursor = (int*)  (ws + 107417616);
  int*            counts = (int*)Zcat;        // NK ints
  int*            counter = counts + NK;      // 1 int (spin counter)

  dim3 blk(256);

  // ---- zero counts + counter ----
  hipMemsetAsync(counts, 0, (NK + 1) * sizeof(int), stream);

  // ---- hist (2500 blocks) || weight prep + poi/road projections (1004) ----
  hist_prep_k<<<3504, blk, 0, stream>>>(dstp, etypep, counts,
                                        loop_w1, loop_w2, time_w,
                                        coef1, basis1, coef2, basis2,
                                        poi_dist, poi_w, poi_b,
                                        road_feat, road_w, road_b,
                                        Wc1, Wc2, TWT, hbuf);

  // ---- scan (157 resident blocks, parallel cross-block base) ----
  scan_all<<<(NK + 1023) / 1024, blk, 0, stream>>>(counts, offs, cursor,
                                                   bsums, counter);

  // ---- fill (1250 blocks) || time GEMM (625 blocks), 512 thr ----
  fill_time_k<<<1875, 512, 0, stream>>>(srcp, dstp, etypep, cursor, ssrc,
                                        time_dist, TWT, time_b, hbuf);

  // ---- layer 1 ----
  agg_k<<<NN * 64 / 256, blk, 0, stream>>>(offs, ssrc, hbuf, Zcat);
  gemm_cat<1><<<(NN + 63) / 64, 512, 0, stream>>>(Zcat, Wc1, bias1, nullptr, hbuf);

  // ---- layer 2 ----
  agg_k<<<NN * 64 / 256, blk, 0, stream>>>(offs, ssrc, hbuf, Zcat);
  gemm_cat<0><<<(NN + 63) / 64, 512, 0, stream>>>(Zcat, Wc2, bias2, out, nullptr);
}

// Round 17
// 370.563 us; speedup vs baseline: 1.6757x; 1.0767x over previous
//
#include <hip/hip_runtime.h>

#define NN 20000
#define NE 640000
#define NR 8
#define NB 8
#define HID 256
#define KPOI 12
#define KTIME 2880
#define KROAD 128
#define NK (NN * NR)    // 160000 (dst,rel) keys
#define NS 9            // 8 relations + self
#define KCAT (NS * HID) // 2304
#define SPLITK 5
#define KCH (KTIME / SPLITK)   // 576 = 9 x 64

typedef __attribute__((ext_vector_type(8))) short bf8_t;   // 8 bf16 = 4 VGPR
typedef __attribute__((ext_vector_type(4))) float f4_t;

__device__ inline unsigned short f2bf(float f) {  // RNE f32->bf16
  unsigned int u = __float_as_uint(f);
  u += 0x7FFF + ((u >> 16) & 1);
  return (unsigned short)(u >> 16);
}
__device__ inline float bf2f(unsigned short h) {
  return __uint_as_float((unsigned int)h << 16);
}

// async global->LDS, 16B per lane; LDS dest = wave-uniform base + lane*16
__device__ inline void gl_lds16(const void* g, void* l) {
  __builtin_amdgcn_global_load_lds(
      (const __attribute__((address_space(1))) void*)g,
      (__attribute__((address_space(3))) void*)l, 16, 0, 0);
}

// ---------------- f32 GEMM tile body (poi/road projections) ----------------
#define BK 16
__device__ inline void sgemm_body(
    int M, int Nn, int K,
    const float* __restrict__ A, int lda,
    const float* __restrict__ B, int ldb,
    const float* __restrict__ bias,
    unsigned short* __restrict__ C, int ldc, int brow, char* lds)
{
  constexpr int BM = 64, BN = 64, TM = 4, TN = 4;
  constexpr int SA = BM + 4;
  constexpr int SB = BN + 4;
  float* As = (float*)lds;
  float* Bs = (float*)(lds + 4352);
  const int tid = threadIdx.x;
  constexpr int TCOLS = BN / TN;
  const int row0 = (tid / TCOLS) * TM;
  const int col0 = (tid % TCOLS) * TN;

  float acc[TM][TN] = {};

  for (int kb = 0; kb < K; kb += BK) {
    {
      int i = tid;
      int r = i >> 2, q = (i & 3) * 4;
      int grow = brow + r, gk = kb + q;
      if (grow < M && gk + 3 < K) {
        float4 v = *(const float4*)(A + (size_t)grow * lda + gk);
        As[(q + 0) * SA + r] = v.x;
        As[(q + 1) * SA + r] = v.y;
        As[(q + 2) * SA + r] = v.z;
        As[(q + 3) * SA + r] = v.w;
      } else {
#pragma unroll
        for (int j = 0; j < 4; ++j)
          As[(q + j) * SA + r] =
              (grow < M && gk + j < K) ? A[(size_t)grow * lda + gk + j] : 0.f;
      }
    }
    {
      int i = tid;
      int k = i / (BN / 4), cq = (i % (BN / 4)) * 4;
      int gk = kb + k;
      float4 v = {0.f, 0.f, 0.f, 0.f};
      if (gk < K) {
        if (cq + 3 < Nn) {
          v = *(const float4*)(B + (size_t)gk * ldb + cq);
        } else {
#pragma unroll
          for (int j = 0; j < 4; ++j)
            if (cq + j < Nn) (&v.x)[j] = B[(size_t)gk * ldb + cq + j];
        }
      }
      *(float4*)(&Bs[k * SB + cq]) = v;
    }
    __syncthreads();
#pragma unroll
    for (int kk = 0; kk < BK; ++kk) {
      float a[TM], bb[TN];
      *(float4*)(&a[0]) = *(const float4*)(&As[kk * SA + row0]);
      *(float4*)(&bb[0]) = *(const float4*)(&Bs[kk * SB + col0]);
#pragma unroll
      for (int i = 0; i < TM; ++i)
#pragma unroll
        for (int j = 0; j < TN; ++j)
          acc[i][j] += a[i] * bb[j];
    }
    __syncthreads();
  }

  float bcache[TN];
#pragma unroll
  for (int j = 0; j < TN; ++j) bcache[j] = bias[col0 + j];
#pragma unroll
  for (int i = 0; i < TM; ++i) {
    int row = brow + row0 + i;
    if (row >= M) continue;
#pragma unroll
    for (int j = 0; j < TN; ++j)
      C[(size_t)row * ldc + col0 + j] = f2bf(acc[i][j] + bcache[j]);
  }
}

// ---------------- merged hist + weight-prep + poi/road projections ---------
__global__ __launch_bounds__(256) void hist_prep_k(
    const int* __restrict__ dstp, const int* __restrict__ etp,
    int* __restrict__ counts,
    const float* __restrict__ loop_w1, const float* __restrict__ loop_w2,
    const float* __restrict__ time_w,
    const float* __restrict__ coef1, const float* __restrict__ basis1,
    const float* __restrict__ coef2, const float* __restrict__ basis2,
    const float* __restrict__ poi_dist, const float* __restrict__ poi_w,
    const float* __restrict__ poi_b,
    const float* __restrict__ road_feat, const float* __restrict__ road_w,
    const float* __restrict__ road_b,
    unsigned short* __restrict__ Wc1, unsigned short* __restrict__ Wc2,
    unsigned short* __restrict__ TWT, unsigned short* __restrict__ hbuf)
{
  __shared__ __align__(16) char lds[8704];
  int b = blockIdx.x;
  if (b < 2500) {   // histogram: 2500*256 == NE exactly
    int e = b * 256 + threadIdx.x;
    atomicAdd(&counts[dstp[e] * NR + etp[e]], 1);
    return;
  }
  b -= 2500;
  const int to = threadIdx.x & 63;
  const int tq = threadIdx.x >> 6;

  if (b < 378) {
    unsigned short (*T)[66] = (unsigned short (*)[66])lds;
    if (b < 256) {        // Wc[lr][o][r*256+i] = sum_q coef*basis[q][i][o]
      const int lr = b >> 4;
      const int tile = b & 15;
      const int i0 = ((tile >> 2) & 3) * 64, o0 = (tile & 3) * 64;
      const float* coef  = (lr < NR) ? coef1 : coef2;
      const float* basis = (lr < NR) ? basis1 : basis2;
      unsigned short* Wc = (lr < NR) ? Wc1 : Wc2;
      const int r = lr & 7;
      float cf[NB];
#pragma unroll
      for (int q = 0; q < NB; ++q) cf[q] = coef[r * NB + q];
#pragma unroll
      for (int k = 0; k < 16; ++k) {
        int i_loc = tq * 16 + k;
        int i = i0 + i_loc;
        float acc = 0.f;
#pragma unroll
        for (int q = 0; q < NB; ++q)
          acc += cf[q] * basis[((size_t)(q * HID + i)) * HID + o0 + to];
        T[i_loc][to] = f2bf(acc);
      }
      __syncthreads();
#pragma unroll
      for (int k = 0; k < 16; ++k) {
        int o_loc = tq * 16 + k;
        Wc[(size_t)(o0 + o_loc) * KCAT + r * HID + i0 + to] = T[to][o_loc];
      }
    } else if (b < 288) { // Wc[l][o][2048+i] = loop_w_l[i][o]
      const int j = b - 256;
      const int layer = j >> 4;
      const int tile = j & 15;
      const int i0 = ((tile >> 2) & 3) * 64, o0 = (tile & 3) * 64;
      const float* lw = layer ? loop_w2 : loop_w1;
      unsigned short* Wc = layer ? Wc2 : Wc1;
#pragma unroll
      for (int k = 0; k < 16; ++k) {
        int i_loc = tq * 16 + k;
        T[i_loc][to] = f2bf(lw[(size_t)(i0 + i_loc) * HID + o0 + to]);
      }
      __syncthreads();
#pragma unroll
      for (int k = 0; k < 16; ++k) {
        int o_loc = tq * 16 + k;
        Wc[(size_t)(o0 + o_loc) * KCAT + NR * HID + i0 + to] = T[to][o_loc];
      }
    } else {              // TWT[c][r] = time_w[r][c], tiled 64x64
      const int j = b - 288;
      const int r0 = (j >> 1) * 64, c0 = (j & 1) * 64;
#pragma unroll
      for (int k = 0; k < 16; ++k) {
        int r_loc = tq * 16 + k;
        T[r_loc][to] = f2bf(time_w[(size_t)(r0 + r_loc) * 128 + c0 + to]);
      }
      __syncthreads();
#pragma unroll
      for (int k = 0; k < 16; ++k) {
        int c_loc = tq * 16 + k;
        TWT[(size_t)(c0 + c_loc) * KTIME + r0 + to] = T[to][c_loc];
      }
    }
  } else if (b < 691) {   // poi projection -> hbuf cols [0,64)
    sgemm_body(NN, 64, KPOI, poi_dist, KPOI, poi_w, 64, poi_b,
               hbuf + 0, HID, (b - 378) * 64, lds);
  } else {                // road projection -> hbuf cols [192,256)
    sgemm_body(NN, 64, KROAD, road_feat, KROAD, road_w, 64, road_b,
               hbuf + 192, HID, (b - 691) * 64, lds);
  }
}

// ---------------- merged scan: parallel cross-block base -------------------
__global__ __launch_bounds__(256) void scan_all(
    const int* __restrict__ counts, int* __restrict__ offs,
    int* __restrict__ cursor, int* __restrict__ bsums,
    int* __restrict__ counter) {
  __shared__ int sh[256];
  const int bid = blockIdx.x;
  const int t = threadIdx.x;
  const int nblk = gridDim.x;
  const int gbase = bid * 1024;
  int v[4], run[4];
  int s = 0;
#pragma unroll
  for (int j = 0; j < 4; ++j) {
    int idx = gbase + t * 4 + j;
    v[j] = (idx < NK) ? counts[idx] : 0;
    s += v[j];
  }
  sh[t] = s;
  __syncthreads();
  for (int off = 1; off < 256; off <<= 1) {
    int x = (t >= off) ? sh[t - off] : 0;
    __syncthreads();
    sh[t] += x;
    __syncthreads();
  }
  {
    int r = sh[t] - s;
#pragma unroll
    for (int j = 0; j < 4; ++j) { run[j] = r; r += v[j]; }
  }
  if (t == 255) {
    bsums[bid] = sh[255];
    __threadfence();
    atomicAdd(counter, 1);
  }
  if (t == 0) {
    while (atomicAdd(counter, 0) < nblk) {}
    __threadfence();
  }
  __syncthreads();
  int bs = (t < nblk) ? atomicAdd(&bsums[t], 0) : 0;
  __syncthreads();
  sh[t] = bs;
  __syncthreads();
  for (int off = 1; off < 256; off <<= 1) {
    int x = (t >= off) ? sh[t - off] : 0;
    __syncthreads();
    sh[t] += x;
    __syncthreads();
  }
  const int base = (bid > 0) ? sh[bid - 1] : 0;
#pragma unroll
  for (int j = 0; j < 4; ++j) {
    int idx = gbase + t * 4 + j;
    if (idx < NK) {
      int val = run[j] + base;
      offs[idx] = val;
      cursor[idx] = val;
    }
  }
  if (bid == 0 && t == 0) offs[NK] = NE;
}

// ---------------- merged cross-block split-K time GEMM + CSR fill ----------
// 5625 blocks x 256 thr, role by b%9: rem<5 -> sk tile (grp=rows, rem=K-chunk);
// rem>=5 -> fill (exact (625*4)*256 == NE edges). Interleaved roles keep both
// resident: fill's atomic latency hides under sk's streaming loads.
__global__ __launch_bounds__(256) void time_fill_k(
    const int* __restrict__ srcp, const int* __restrict__ dstp,
    const int* __restrict__ etp, int* __restrict__ cursor,
    unsigned short* __restrict__ ssrc,
    const float* __restrict__ A,            // [NN][2880] f32
    const unsigned short* __restrict__ BT,  // [128][2880] bf16
    float* __restrict__ TP)                 // [SPLITK][NN][128] f32 partials
{
  __shared__ __align__(16) char lds[20480];
  const int b = blockIdx.x;
  const int grp = b / 9, rem = b % 9;
  if (rem >= 5) {   // ---- fill role ----
    int e = (grp * 4 + (rem - 5)) * 256 + threadIdx.x;   // < 640000 exact
    int key = dstp[e] * NR + etp[e];
    int p = atomicAdd(&cursor[key], 1);
    ssrc[p] = (unsigned short)srcp[e];
    return;
  }
  // ---- sk role: rows grp*32..+31, K-chunk rem ----
  char* ldsA = lds;            // 4 KB
  char* ldsB = lds + 4096;     // 16 KB
  const int tid = threadIdx.x;
  const int lane = tid & 63;
  const int w = tid >> 6;            // 0..3 -> col block w*32
  const int brow = grp * 32;
  const int kb0 = rem * KCH;

  f4_t acc[2][2];
#pragma unroll
  for (int i = 0; i < 2; ++i)
#pragma unroll
    for (int j = 0; j < 2; ++j) acc[i][j] = (f4_t){0.f, 0.f, 0.f, 0.f};

  for (int kb = kb0; kb < kb0 + KCH; kb += 64) {
    {  // A: 32 rows x 64 k, f32 -> bf16
      int r = tid >> 3, c8 = tid & 7;
      const float* ap = A + (size_t)(brow + r) * KTIME + kb + c8 * 8;
      f4_t v0 = *(const f4_t*)ap;
      f4_t v1 = *(const f4_t*)(ap + 4);
      unsigned short hh[8];
#pragma unroll
      for (int j = 0; j < 4; ++j) { hh[j] = f2bf(v0[j]); hh[4 + j] = f2bf(v1[j]); }
      *(bf8_t*)(ldsA + r * 128 + ((c8 * 16) ^ ((r & 7) << 4))) = *(bf8_t*)hh;
    }
#pragma unroll
    for (int it = 0; it < 4; ++it) {  // B: 128 rows x 64 k
      int slot = tid + it * 256;
      int r = slot >> 3, c8 = slot & 7;
      bf8_t v = *(const bf8_t*)(BT + (size_t)r * KTIME + kb + c8 * 8);
      *(bf8_t*)(ldsB + r * 128 + ((c8 * 16) ^ ((r & 7) << 4))) = v;
    }
    __syncthreads();
#pragma unroll
    for (int ks = 0; ks < 2; ++ks) {
      const int kbyte = ks * 64 + (lane >> 4) * 16;
      bf8_t af[2], bfr[2];
#pragma unroll
      for (int mi = 0; mi < 2; ++mi) {
        int m = mi * 16 + (lane & 15);
        af[mi] = *(const bf8_t*)(ldsA + m * 128 + (kbyte ^ ((m & 7) << 4)));
      }
#pragma unroll
      for (int ni = 0; ni < 2; ++ni) {
        int n = w * 32 + ni * 16 + (lane & 15);
        bfr[ni] = *(const bf8_t*)(ldsB + n * 128 + (kbyte ^ ((n & 7) << 4)));
      }
#pragma unroll
      for (int mi = 0; mi < 2; ++mi)
#pragma unroll
        for (int ni = 0; ni < 2; ++ni)
          acc[mi][ni] = __builtin_amdgcn_mfma_f32_16x16x32_bf16(
              af[mi], bfr[ni], acc[mi][ni], 0, 0, 0);
    }
    __syncthreads();
  }

  float* tp = TP + (size_t)rem * NN * 128;
  const int rq = (lane >> 4) * 4;
  const int cl = lane & 15;
#pragma unroll
  for (int ni = 0; ni < 2; ++ni) {
    int c = w * 32 + ni * 16 + cl;
#pragma unroll
    for (int mi = 0; mi < 2; ++mi) {
#pragma unroll
      for (int j = 0; j < 4; ++j) {
        int row = brow + mi * 16 + rq + j;
        tp[(size_t)row * 128 + c] = acc[mi][ni][j];
      }
    }
  }
}

// ---------------- time finish: hbuf[:,64:192] = bf16(sum_k TP + bias) ------
__global__ __launch_bounds__(256) void time_finish(
    const float* __restrict__ TP, const float* __restrict__ bias,
    unsigned short* __restrict__ featb) {
  int i = blockIdx.x * 256 + threadIdx.x;   // over NN*32 float4 groups
  if (i >= NN * 32) return;
  int row = i >> 5, c4 = (i & 31) * 4;
  f4_t s = *(const f4_t*)(TP + (size_t)row * 128 + c4);
#pragma unroll
  for (int k = 1; k < SPLITK; ++k) {
    f4_t v = *(const f4_t*)(TP + (size_t)k * NN * 128 + (size_t)row * 128 + c4);
    s.x += v.x; s.y += v.y; s.z += v.z; s.w += v.w;
  }
  f4_t b = *(const f4_t*)(bias + c4);
  unsigned short h[4] = {f2bf(s.x + b.x), f2bf(s.y + b.y),
                         f2bf(s.z + b.z), f2bf(s.w + b.w)};
  *(ushort4*)(featb + (size_t)row * 256 + 64 + c4) = *(ushort4*)h;
}

// ---------------- CSR aggregation: one wave per dst, all 9 slices ----------
__global__ __launch_bounds__(256) void agg_k(
    const int* __restrict__ offs, const unsigned short* __restrict__ ssrc,
    const unsigned short* __restrict__ hin, unsigned short* __restrict__ Zc) {
  int d = (blockIdx.x * 256 + threadIdx.x) >> 6;
  int lane = threadIdx.x & 63;
  if (d >= NN) return;
  unsigned short* zrow = Zc + (size_t)d * KCAT;
  *(ushort4*)(zrow + NR * HID + lane * 4) =
      *(const ushort4*)(hin + (size_t)d * HID + lane * 4);
  int ob[NR + 1];
#pragma unroll
  for (int r = 0; r <= NR; ++r) ob[r] = offs[d * NR + r];
#pragma unroll 1
  for (int q = 0; q < NR; ++q) {
    int e = ob[q], hi = ob[q + 1];
    f4_t az = {0.f, 0.f, 0.f, 0.f};
    for (; e + 4 <= hi; e += 4) {
      int s0 = ssrc[e], s1 = ssrc[e + 1], s2 = ssrc[e + 2], s3 = ssrc[e + 3];
      ushort4 u0 = *(const ushort4*)(hin + (size_t)s0 * HID + lane * 4);
      ushort4 u1 = *(const ushort4*)(hin + (size_t)s1 * HID + lane * 4);
      ushort4 u2 = *(const ushort4*)(hin + (size_t)s2 * HID + lane * 4);
      ushort4 u3 = *(const ushort4*)(hin + (size_t)s3 * HID + lane * 4);
      az.x += (bf2f(u0.x) + bf2f(u1.x)) + (bf2f(u2.x) + bf2f(u3.x));
      az.y += (bf2f(u0.y) + bf2f(u1.y)) + (bf2f(u2.y) + bf2f(u3.y));
      az.z += (bf2f(u0.z) + bf2f(u1.z)) + (bf2f(u2.z) + bf2f(u3.z));
      az.w += (bf2f(u0.w) + bf2f(u1.w)) + (bf2f(u2.w) + bf2f(u3.w));
    }
    for (; e < hi; ++e) {
      int s = ssrc[e];
      ushort4 u = *(const ushort4*)(hin + (size_t)s * HID + lane * 4);
      az.x += bf2f(u.x); az.y += bf2f(u.y);
      az.z += bf2f(u.z); az.w += bf2f(u.w);
    }
    unsigned short hz[4] = {f2bf(az.x), f2bf(az.y), f2bf(az.z), f2bf(az.w)};
    *(ushort4*)(zrow + q * HID + lane * 4) = *(ushort4*)hz;
  }
}

// ---------------- layer GEMM: C[64x256] = Zcat @ Wcat + bias ---------------
template<int EPI>
__global__ __launch_bounds__(512) void gemm_cat(
    const unsigned short* __restrict__ Zc,    // [NN][KCAT]
    const unsigned short* __restrict__ Wc,    // [256][KCAT]
    const float* __restrict__ bias,
    float* __restrict__ C, unsigned short* __restrict__ hb)
{
  __shared__ __align__(16) char At[64 * 128];    // 8 KB
  __shared__ __align__(16) char Bt[256 * 128];   // 32 KB
  const int tid = threadIdx.x;
  const int lane = tid & 63;
  const int w = tid >> 6;
  const int wm = w >> 2;         // rows wm*32..+31
  const int wn = w & 3;          // cols wn*64..+63
  const int brow = blockIdx.x * 64;
  const bool full = (brow + 64 <= NN);
  const int c8sw = (lane & 7) ^ (lane >> 3);

  f4_t acc[2][4];
#pragma unroll
  for (int i = 0; i < 2; ++i)
#pragma unroll
    for (int j = 0; j < 4; ++j) acc[i][j] = (f4_t){0.f, 0.f, 0.f, 0.f};

  for (int kb = 0; kb < KCAT; kb += 64) {
    if (full) {  // A via global_load_lds: wave w -> rows w*8..w*8+7
      int row = (w << 3) + (lane >> 3);
      gl_lds16(Zc + (size_t)(brow + row) * KCAT + kb + c8sw * 8,
               At + (w << 10));
    } else {     // guarded reg-staged fallback (last block only)
      int r = tid >> 3, c8 = tid & 7;
      int grow = brow + r;
      bf8_t v = {0, 0, 0, 0, 0, 0, 0, 0};
      if (grow < NN) v = *(const bf8_t*)(Zc + (size_t)grow * KCAT + kb + c8 * 8);
      *(bf8_t*)(At + r * 128 + ((c8 * 16) ^ ((r & 7) << 4))) = v;
    }
#pragma unroll
    for (int it = 0; it < 4; ++it) {  // B via global_load_lds
      int n0 = (w << 3) + it * 64;
      int n = n0 + (lane >> 3);
      gl_lds16(Wc + (size_t)n * KCAT + kb + c8sw * 8, Bt + n0 * 128);
    }
    __syncthreads();
#pragma unroll
    for (int ks = 0; ks < 2; ++ks) {
      const int kbyte = ks * 64 + (lane >> 4) * 16;
      bf8_t af[2], bfr[4];
#pragma unroll
      for (int mi = 0; mi < 2; ++mi) {
        int m = wm * 32 + mi * 16 + (lane & 15);
        af[mi] = *(const bf8_t*)(At + m * 128 + (kbyte ^ ((m & 7) << 4)));
      }
#pragma unroll
      for (int ni = 0; ni < 4; ++ni) {
        int n = wn * 64 + ni * 16 + (lane & 15);
        bfr[ni] = *(const bf8_t*)(Bt + n * 128 + (kbyte ^ ((n & 7) << 4)));
      }
#pragma unroll
      for (int mi = 0; mi < 2; ++mi)
#pragma unroll
        for (int ni = 0; ni < 4; ++ni)
          acc[mi][ni] = __builtin_amdgcn_mfma_f32_16x16x32_bf16(
              af[mi], bfr[ni], acc[mi][ni], 0, 0, 0);
    }
    __syncthreads();
  }

  const int rq = (lane >> 4) * 4;
  const int cl = lane & 15;
#pragma unroll
  for (int ni = 0; ni < 4; ++ni) {
    int c = wn * 64 + ni * 16 + cl;
    float bv = bias[c];
#pragma unroll
    for (int mi = 0; mi < 2; ++mi) {
#pragma unroll
      for (int j = 0; j < 4; ++j) {
        int row = brow + wm * 32 + mi * 16 + rq + j;
        if (row < NN) {
          size_t o = (size_t)row * HID + c;
          float v = acc[mi][ni][j] + bv;
          if (EPI == 0) C[o] = v;
          else          hb[o] = f2bf(fmaxf(v, 0.f));
        }
      }
    }
  }
}

extern "C" void kernel_launch(void* const* d_in, const int* in_sizes, int n_in,
                              void* d_out, int out_size, void* d_ws, size_t ws_size,
                              hipStream_t stream) {
  const int*   srcp      = (const int*)d_in[0];
  const int*   dstp      = (const int*)d_in[1];
  const int*   etypep    = (const int*)d_in[2];
  const float* poi_dist  = (const float*)d_in[3];
  const float* time_dist = (const float*)d_in[4];
  const float* road_feat = (const float*)d_in[5];
  const float* poi_w     = (const float*)d_in[6];
  const float* poi_b     = (const float*)d_in[7];
  const float* time_w    = (const float*)d_in[8];
  const float* time_b    = (const float*)d_in[9];
  const float* road_w    = (const float*)d_in[10];
  const float* road_b    = (const float*)d_in[11];
  const float* basis1    = (const float*)d_in[12];
  const float* coef1     = (const float*)d_in[13];
  const float* loop_w1   = (const float*)d_in[14];
  const float* bias1     = (const float*)d_in[15];
  const float* basis2    = (const float*)d_in[16];
  const float* coef2     = (const float*)d_in[17];
  const float* loop_w2   = (const float*)d_in[18];
  const float* bias2     = (const float*)d_in[19];

  float* out = (float*)d_out;

  // ws layout (bytes), total ~108.1 MB (ws_size ~921 MB):
  //   Wc1  bf16 @ 0           (1,179,648)   [256][2304]
  //   Wc2  bf16 @ 1,179,648   (1,179,648)
  //   TWT  bf16 @ 2,359,296   (737,280)
  //   hbuf bf16 @ 3,096,576   (10,240,000)  feat; then relu(h1)
  //   Zcat bf16 @ 13,336,576  (92,160,000)  [NN][2304]
  //   offs      @ 105,496,576 (640,016)
  //   bsums     @ 106,136,592 (1,024)
  //   ssrc u16  @ 106,137,616 (1,280,000)
  //   cursor    @ 107,417,616 (640,000)
  // aliases into Zcat region (each dead before Zcat's first write by agg):
  //   counts (NK ints) + counter @ Zcat base; TP f32 (51.2 MB) @ Zcat base
  //   (TP written after scan consumed counts; read by time_finish before agg)
  char* ws = (char*)d_ws;
  unsigned short* Wc1    = (unsigned short*)(ws);
  unsigned short* Wc2    = (unsigned short*)(ws + 1179648);
  unsigned short* TWT    = (unsigned short*)(ws + 2359296);
  unsigned short* hbuf   = (unsigned short*)(ws + 3096576);
  unsigned short* Zcat   = (unsigned short*)(ws + 13336576);
  int*            offs   = (int*)  (ws + 105496576);
  int*            bsums  = (int*)  (ws + 106136592);
  unsigned short* ssrc   = (unsigned short*)(ws + 106137616);
  int*            cursor = (int*)  (ws + 107417616);
  int*            counts = (int*)Zcat;        // NK ints
  int*            counter = counts + NK;      // 1 int (spin counter)
  float*          TP     = (float*)Zcat;      // [SPLITK][NN][128], after scan

  dim3 blk(256);

  // ---- zero counts + counter ----
  hipMemsetAsync(counts, 0, (NK + 1) * sizeof(int), stream);

  // ---- hist (2500 blocks) || weight prep + poi/road projections (1004) ----
  hist_prep_k<<<3504, blk, 0, stream>>>(dstp, etypep, counts,
                                        loop_w1, loop_w2, time_w,
                                        coef1, basis1, coef2, basis2,
                                        poi_dist, poi_w, poi_b,
                                        road_feat, road_w, road_b,
                                        Wc1, Wc2, TWT, hbuf);

  // ---- scan (157 resident blocks, parallel cross-block base) ----
  scan_all<<<(NK + 1023) / 1024, blk, 0, stream>>>(counts, offs, cursor,
                                                   bsums, counter);

  // ---- cross-block split-K time GEMM (3125) || CSR fill (2500), interleaved
  time_fill_k<<<5625, blk, 0, stream>>>(srcp, dstp, etypep, cursor, ssrc,
                                        time_dist, TWT, TP);
  time_finish<<<(NN * 32 + 255) / 256, blk, 0, stream>>>(TP, time_b, hbuf);

  // ---- layer 1 ----
  agg_k<<<NN * 64 / 256, blk, 0, stream>>>(offs, ssrc, hbuf, Zcat);
  gemm_cat<1><<<(NN + 63) / 64, 512, 0, stream>>>(Zcat, Wc1, bias1, nullptr, hbuf);

  // ---- layer 2 ----
  agg_k<<<NN * 64 / 256, blk, 0, stream>>>(offs, ssrc, hbuf, Zcat);
  gemm_cat<0><<<(NN + 63) / 64, 512, 0, stream>>>(Zcat, Wc2, bias2, out, nullptr);
}